// Round 7
// baseline (239.657 us; speedup 1.0000x reference)
//
#include <hip/hip_runtime.h>
#include <math.h>

#define BN_EPS_F 1e-5f

// ---------------------------------------------------------------------------
// Layer 1: K=8 — memory-bound, one thread per 4 outputs.
// ---------------------------------------------------------------------------
__global__ __launch_bounds__(256)
void l1_kernel(const float* __restrict__ G, const float* __restrict__ W1,
               const float* __restrict__ bias, const float* __restrict__ gamma,
               const float* __restrict__ beta, const float* __restrict__ mean,
               const float* __restrict__ var, float* __restrict__ h1)
{
    const int m = blockIdx.x;
    const int t = threadIdx.x;
    if (t >= 250) return;
    const int n = 4 * t;

    float4 g0 = *(const float4*)(G + (size_t)m * 8 + 0);
    float4 g1 = *(const float4*)(G + (size_t)m * 8 + 4);

    float4 bi = *(const float4*)(bias + n);
    float4 ga = *(const float4*)(gamma + n);
    float4 be = *(const float4*)(beta + n);
    float4 mu = *(const float4*)(mean + n);
    float4 va = *(const float4*)(var + n);

    float4 out;
    float* op = &out.x;
    const float* bip = &bi.x; const float* gap = &ga.x; const float* bep = &be.x;
    const float* mup = &mu.x; const float* vap = &va.x;
#pragma unroll
    for (int j = 0; j < 4; ++j) {
        const float* w = W1 + (size_t)(n + j) * 8;
        float4 w0 = *(const float4*)(w + 0);
        float4 w1 = *(const float4*)(w + 4);
        float d = g0.x*w0.x + g0.y*w0.y + g0.z*w0.z + g0.w*w0.w
                + g1.x*w1.x + g1.y*w1.y + g1.z*w1.z + g1.w*w1.w;
        float s  = gap[j] * rsqrtf(vap[j] + BN_EPS_F);
        float t0 = fmaf(s, bip[j] - mup[j], bep[j]);
        op[j] = fmaxf(fmaf(s, d, t0), 0.f);
    }
    *(float4*)(h1 + (size_t)m * 1000 + n) = out;
}

// ---------------------------------------------------------------------------
// fp32 NT GEMM — 64(M) x 128(N) tile, BK=32, 128 threads = 2 waves (wave w
// owns N-half w*64). Lane (tx,ty) in 8x8 grid computes an 8Mx8N tile:
// rows {ty*4..+3} ∪ {32+ty*4..+3}, cols w*64+tx*8..+7. Per kk: 4 x
// ds_read_b128 per 64 FMA (1.0 B/FMA — LDS-return-path optimal for fp32).
// Single LDS buffer, straight-line staging, no cross-barrier register
// liveness (round-5 spill-free recipe). __launch_bounds__(128,1): VGPR cap
// 256 -> no spill at ~170 (round-3 lesson: the ",2" cap caused the spills).
// MODE 0: BN+relu, MODE 1: BN+sigmoid, MODE 2: raw partial (split-K via z).
// Requires: ldc >= (max col < N)+8; K,kchunk % 4 == 0.
// ---------------------------------------------------------------------------
template<int MODE>
__global__ __launch_bounds__(128, 1)
void gemm_w(const float* __restrict__ A, int K, int lda,
            const float* __restrict__ B, int N, int ldb, int kchunk,
            const float* __restrict__ bias, const float* __restrict__ gamma,
            const float* __restrict__ beta, const float* __restrict__ mean,
            const float* __restrict__ var,
            float* __restrict__ C, int ldc, size_t zstride)
{
    __shared__ float As[32][68];
    __shared__ float Bs[32][132];

    const int tid  = threadIdx.x;
    const int w    = tid >> 6;
    const int lane = tid & 63;
    const int tx   = lane & 7, ty = lane >> 3;
    const int m0   = blockIdx.y * 64;
    const int n0   = blockIdx.x * 128;
    const int z    = blockIdx.z;
    const int ks   = z * kchunk;
    const int ke   = min(K, ks + kchunk);
    const int nt   = (ke - ks + 31) >> 5;

    const int srow = tid >> 3;     // 0..15
    const int skq  = tid & 7;      // 16B chunk within BK=32

    float acc[8][8];
#pragma unroll
    for (int i = 0; i < 8; ++i)
#pragma unroll
        for (int j = 0; j < 8; ++j) acc[i][j] = 0.f;

    const int ar = ty * 4;             // A rows ar..ar+3 and ar+32..ar+35
    const int br = w * 64 + tx * 8;    // B cols br..br+7
    const float4 zf4 = make_float4(0.f, 0.f, 0.f, 0.f);

    for (int t = 0; t < nt; ++t) {
        // ---- stage tile t (load -> immediate LDS write; nothing crosses barrier)
        {
            const int kg  = ks + t * 32 + 4 * skq;
            const bool kv = kg < ke;                 // ke%4==0 -> all-or-nothing
#pragma unroll
            for (int i = 0; i < 4; ++i) {            // A: rows srow+16i
                const int r = srow + 16 * i;
                float4 v = kv ? *(const float4*)(A + (size_t)(m0 + r) * lda + kg) : zf4;
                As[4*skq+0][r] = v.x; As[4*skq+1][r] = v.y;
                As[4*skq+2][r] = v.z; As[4*skq+3][r] = v.w;
            }
#pragma unroll
            for (int i = 0; i < 8; ++i) {            // B: rows srow+16i
                const int r = srow + 16 * i;
                float4 v = (kv && (n0 + r) < N)
                    ? *(const float4*)(B + (size_t)(n0 + r) * ldb + kg) : zf4;
                Bs[4*skq+0][r] = v.x; Bs[4*skq+1][r] = v.y;
                Bs[4*skq+2][r] = v.z; Bs[4*skq+3][r] = v.w;
            }
        }
        __syncthreads();
        // ---- MAC: 4 x ds_read_b128 per 64 FMA
#pragma unroll 4
        for (int kk = 0; kk < 32; ++kk) {
            float4 x0 = *(const float4*)&As[kk][ar];
            float4 x1 = *(const float4*)&As[kk][ar + 32];
            float4 y0 = *(const float4*)&Bs[kk][br];
            float4 y1 = *(const float4*)&Bs[kk][br + 4];
            float a[8] = {x0.x,x0.y,x0.z,x0.w,x1.x,x1.y,x1.z,x1.w};
            float b[8] = {y0.x,y0.y,y0.z,y0.w,y1.x,y1.y,y1.z,y1.w};
#pragma unroll
            for (int i = 0; i < 8; ++i)
#pragma unroll
                for (int j = 0; j < 8; ++j)
                    acc[i][j] = fmaf(a[i], b[j], acc[i][j]);
        }
        __syncthreads();
    }

    // ---- epilogue ----
    const int col = n0 + br;
    if (col < N) {     // col%8==0; ldc guarantees col..col+7 in-bounds;
                       // cols >= N hold zeros (B staged 0) and are never read
        if (MODE == 2) {
            float* Cz = C + (size_t)z * zstride;
#pragma unroll
            for (int i = 0; i < 8; ++i) {
                const int row = m0 + (i < 4 ? ar + i : 32 + ar + i - 4);
                float* cr = Cz + (size_t)row * ldc + col;
                *(float4*)(cr)     = make_float4(acc[i][0],acc[i][1],acc[i][2],acc[i][3]);
                *(float4*)(cr + 4) = make_float4(acc[i][4],acc[i][5],acc[i][6],acc[i][7]);
            }
        } else {
            float4 ga0 = *(const float4*)(gamma + col);
            float4 va0 = *(const float4*)(var + col);
            float4 bi0 = *(const float4*)(bias + col);
            float4 mu0 = *(const float4*)(mean + col);
            float4 be0 = *(const float4*)(beta + col);
            float4 ga1 = *(const float4*)(gamma + col + 4);
            float4 va1 = *(const float4*)(var + col + 4);
            float4 bi1 = *(const float4*)(bias + col + 4);
            float4 mu1 = *(const float4*)(mean + col + 4);
            float4 be1 = *(const float4*)(beta + col + 4);
            float s[8], t8[8];
            s[0]=ga0.x*rsqrtf(va0.x+BN_EPS_F); s[1]=ga0.y*rsqrtf(va0.y+BN_EPS_F);
            s[2]=ga0.z*rsqrtf(va0.z+BN_EPS_F); s[3]=ga0.w*rsqrtf(va0.w+BN_EPS_F);
            s[4]=ga1.x*rsqrtf(va1.x+BN_EPS_F); s[5]=ga1.y*rsqrtf(va1.y+BN_EPS_F);
            s[6]=ga1.z*rsqrtf(va1.z+BN_EPS_F); s[7]=ga1.w*rsqrtf(va1.w+BN_EPS_F);
            t8[0]=fmaf(s[0],bi0.x-mu0.x,be0.x); t8[1]=fmaf(s[1],bi0.y-mu0.y,be0.y);
            t8[2]=fmaf(s[2],bi0.z-mu0.z,be0.z); t8[3]=fmaf(s[3],bi0.w-mu0.w,be0.w);
            t8[4]=fmaf(s[4],bi1.x-mu1.x,be1.x); t8[5]=fmaf(s[5],bi1.y-mu1.y,be1.y);
            t8[6]=fmaf(s[6],bi1.z-mu1.z,be1.z); t8[7]=fmaf(s[7],bi1.w-mu1.w,be1.w);
#pragma unroll
            for (int i = 0; i < 8; ++i) {
                const int row = m0 + (i < 4 ? ar + i : 32 + ar + i - 4);
                float y[8];
#pragma unroll
                for (int j = 0; j < 8; ++j) {
                    float yy = fmaf(s[j], acc[i][j], t8[j]);
                    if (MODE == 0) yy = fmaxf(yy, 0.f);
                    else           yy = 1.f / (1.f + expf(-yy));
                    y[j] = yy;
                }
                float* cr = C + (size_t)row * ldc + col;
                *(float4*)(cr)     = make_float4(y[0],y[1],y[2],y[3]);
                *(float4*)(cr + 4) = make_float4(y[4],y[5],y[6],y[7]);
            }
        }
    }
}

// ---------------------------------------------------------------------------
// Split-K=2 reduce for layer 2 + BN + relu. Writes h2 over PANEL 1 (in-place
// same-index), freeing [0 .. panel1) contiguously for GEMM3 partials.
// ---------------------------------------------------------------------------
__global__ __launch_bounds__(256)
void reduce2_relu(float* __restrict__ part,     // panel0; panel1 at +2048000
                  const float* __restrict__ bias, const float* __restrict__ gamma,
                  const float* __restrict__ beta, const float* __restrict__ mean,
                  const float* __restrict__ var)
{
    const int i = blockIdx.x * 256 + threadIdx.x;
    if (i >= 2048 * 250) return;
    const int m = i / 250;
    const int n = (i % 250) * 4;
    const size_t off = (size_t)m * 1000 + n;
    float4 a = *(const float4*)(part + off);
    float4 b = *(const float4*)(part + 2048000 + off);
    float4 ga = *(const float4*)(gamma + n);
    float4 va = *(const float4*)(var + n);
    float4 bi = *(const float4*)(bias + n);
    float4 mu = *(const float4*)(mean + n);
    float4 be = *(const float4*)(beta + n);
    float s0 = ga.x*rsqrtf(va.x+BN_EPS_F), s1 = ga.y*rsqrtf(va.y+BN_EPS_F);
    float s2 = ga.z*rsqrtf(va.z+BN_EPS_F), s3 = ga.w*rsqrtf(va.w+BN_EPS_F);
    float4 out;
    out.x = fmaxf(fmaf(s0, a.x + b.x + bi.x - mu.x, be.x), 0.f);
    out.y = fmaxf(fmaf(s1, a.y + b.y + bi.y - mu.y, be.y), 0.f);
    out.z = fmaxf(fmaf(s2, a.z + b.z + bi.z - mu.z, be.z), 0.f);
    out.w = fmaxf(fmaf(s3, a.w + b.w + bi.w - mu.w, be.w), 0.f);
    *(float4*)(part + 2048000 + off) = out;     // h2 = panel1
}

// ---------------------------------------------------------------------------
// Split-K reduce for layer 3 + BN + sigmoid -> p (2048 x 300)
// ---------------------------------------------------------------------------
__global__ __launch_bounds__(256)
void reduce3_sigmoid(const float* __restrict__ part, int nz, size_t pstride,
                     const float* __restrict__ bias, const float* __restrict__ gamma,
                     const float* __restrict__ beta, const float* __restrict__ mean,
                     const float* __restrict__ var, float* __restrict__ p)
{
    const int i = blockIdx.x * 256 + threadIdx.x;
    if (i >= 2048 * 75) return;
    const int m = i / 75;
    const int n = (i % 75) * 4;
    const size_t off = (size_t)m * 304 + n;
    float d0 = 0.f, d1 = 0.f, d2 = 0.f, d3 = 0.f;
    for (int zz = 0; zz < nz; ++zz) {
        float4 v = *(const float4*)(part + zz * pstride + off);
        d0 += v.x; d1 += v.y; d2 += v.z; d3 += v.w;
    }
    float4 ga = *(const float4*)(gamma + n);
    float4 va = *(const float4*)(var + n);
    float4 bi = *(const float4*)(bias + n);
    float4 mu = *(const float4*)(mean + n);
    float4 be = *(const float4*)(beta + n);
    float s0 = ga.x*rsqrtf(va.x+BN_EPS_F), s1 = ga.y*rsqrtf(va.y+BN_EPS_F);
    float s2 = ga.z*rsqrtf(va.z+BN_EPS_F), s3 = ga.w*rsqrtf(va.w+BN_EPS_F);
    float4 out;
    out.x = 1.f/(1.f+expf(-(fmaf(s0, d0 + bi.x - mu.x, be.x))));
    out.y = 1.f/(1.f+expf(-(fmaf(s1, d1 + bi.y - mu.y, be.y))));
    out.z = 1.f/(1.f+expf(-(fmaf(s2, d2 + bi.z - mu.z, be.z))));
    out.w = 1.f/(1.f+expf(-(fmaf(s3, d3 + bi.w - mu.w, be.w))));
    *(float4*)(p + (size_t)m * 300 + n) = out;
}

// ---------------------------------------------------------------------------
// Lorentz spectrum: one block per batch row; oscillator params packed as
// float4 in LDS (1 ds_read_b128 per oscillator instead of 4 b32).
// ---------------------------------------------------------------------------
__global__ __launch_bounds__(320)
void lorentz_kernel(const float* __restrict__ P,     // 2048 x 300
                    const float* __restrict__ G,     // 2048 x 8
                    const float* __restrict__ wgrid, // 300
                    float* __restrict__ T)           // 2048 x 300
{
    __shared__ float4 s_pk[100];   // {w0^2, wp^2, wp^2*g, g^2}
    const int b   = blockIdx.x;
    const int tid = threadIdx.x;
    if (tid < 100) {
        const float* p = P + (size_t)b*300 + 3*tid;
        const float w0 = p[0]*5.f;
        const float wp = p[1]*5.f;
        const float g  = p[2]*0.5f;
        s_pk[tid] = make_float4(w0*w0, wp*wp, wp*wp*g, g*g);
    }
    __syncthreads();
    if (tid < 300) {
        const float wg = wgrid[tid];
        const float w2 = wg*wg;
        float e1 = 0.f, e2s = 0.f;
#pragma unroll 10
        for (int l = 0; l < 100; ++l) {
            const float4 v    = s_pk[l];
            const float s1    = v.x - w2;
            const float denom = fmaf(s1, s1, w2 * v.w);
            const float r     = __builtin_amdgcn_rcpf(denom);
            e1  = fmaf(v.y*s1, r, e1);
            e2s = fmaf(v.z,    r, e2s);
        }
        e1 += 10.f;
        const float e2  = e2s * wg;
        const float mag = sqrtf(fmaf(e1, e1, e2*e2));
        const float nn  = sqrtf(0.5f*(mag + e1));
        const float kk  = sqrtf(fmaxf(0.5f*(mag - e1), 0.f));
        const float d   = fmaxf(fmaxf(G[b*8+4], G[b*8+5]),
                                fmaxf(G[b*8+6], G[b*8+7]));
        const float ab  = expf(-0.006283185307179586f * d * kk);
        const float np1 = nn + 1.f;
        const float Tv  = 4.f*nn / fmaf(np1, np1, kk*kk) * ab;
        T[(size_t)b*300 + tid] = Tv;
    }
}

extern "C" void kernel_launch(void* const* d_in, const int* in_sizes, int n_in,
                              void* d_out, int out_size, void* d_ws, size_t ws_size,
                              hipStream_t stream) {
    const float* G      = (const float*)d_in[0];
    const float* W1     = (const float*)d_in[1];
    const float* b1     = (const float*)d_in[2];
    const float* gamma1 = (const float*)d_in[3];
    const float* beta1  = (const float*)d_in[4];
    const float* mean1  = (const float*)d_in[5];
    const float* var1   = (const float*)d_in[6];
    const float* W2     = (const float*)d_in[7];
    const float* b2     = (const float*)d_in[8];
    const float* gamma2 = (const float*)d_in[9];
    const float* beta2  = (const float*)d_in[10];
    const float* mean2  = (const float*)d_in[11];
    const float* var2   = (const float*)d_in[12];
    const float* W3     = (const float*)d_in[13];
    const float* b3     = (const float*)d_in[14];
    const float* gamma3 = (const float*)d_in[15];
    const float* beta3  = (const float*)d_in[16];
    const float* mean3  = (const float*)d_in[17];
    const float* var3   = (const float*)d_in[18];
    const float* wgrid  = (const float*)d_in[19];

    float* ws = (float*)d_ws;
    float* T  = (float*)d_out;

    // Layout (24.576 MB total — proven capacity):
    //   h1    @ [0          .. 2,048,000)
    //   part2 @ [2,048,000  .. 6,144,000)  2 panels; h2 = panel1 (in-place)
    //   part3 @ [0          .. 3,112,960)  5 panels (over dead h1+panel0)
    //   p     @ [3,112,960  .. 3,727,360)  (over dead panel0 tail)
    float* h1    = ws;
    float* part2 = ws + 2048000;
    float* h2    = ws + 4096000;       // = part2 panel1
    float* part3 = ws;
    float* p     = ws + 3112960;

    // Layer 1 (K=8, memory-bound)
    l1_kernel<<<2048, 256, 0, stream>>>(G, W1, b1, gamma1, beta1, mean1, var1, h1);

    // Layer 2: split-K=2 (grid 8n x 32m x 2z = 512 blocks = 2/CU)
    gemm_w<2><<<dim3(8, 32, 2), 128, 0, stream>>>(
        h1, 1000, 1000, W2, 1000, 1000, 500,
        nullptr, nullptr, nullptr, nullptr, nullptr, part2, 1000, 2048000);
    reduce2_relu<<<2000, 256, 0, stream>>>(part2, b2, gamma2, beta2, mean2, var2);

    // Layer 3: split-K=5 (grid 3n x 32m x 5z = 480 blocks <= 2/CU, balanced)
    gemm_w<2><<<dim3(3, 32, 5), 128, 0, stream>>>(
        h2, 1000, 1000, W3, 300, 1000, 200,
        nullptr, nullptr, nullptr, nullptr, nullptr, part3, 304, 622592);

    // Reduce partials + BN + sigmoid -> p
    reduce3_sigmoid<<<600, 256, 0, stream>>>(part3, 5, 622592,
        b3, gamma3, beta3, mean3, var3, p);

    // Lorentz spectrum -> T
    lorentz_kernel<<<2048, 320, 0, stream>>>(p, G, wgrid, T);
}

// Round 8
// 195.433 us; speedup vs baseline: 1.2263x; 1.2263x over previous
//
#include <hip/hip_runtime.h>
#include <math.h>

#define BN_EPS_F 1e-5f

// ---------------------------------------------------------------------------
// Layer 1: K=8 — memory-bound, one thread per 4 outputs.
// ---------------------------------------------------------------------------
__global__ __launch_bounds__(256)
void l1_kernel(const float* __restrict__ G, const float* __restrict__ W1,
               const float* __restrict__ bias, const float* __restrict__ gamma,
               const float* __restrict__ beta, const float* __restrict__ mean,
               const float* __restrict__ var, float* __restrict__ h1)
{
    const int m = blockIdx.x;
    const int t = threadIdx.x;
    if (t >= 250) return;
    const int n = 4 * t;

    float4 g0 = *(const float4*)(G + (size_t)m * 8 + 0);
    float4 g1 = *(const float4*)(G + (size_t)m * 8 + 4);

    float4 bi = *(const float4*)(bias + n);
    float4 ga = *(const float4*)(gamma + n);
    float4 be = *(const float4*)(beta + n);
    float4 mu = *(const float4*)(mean + n);
    float4 va = *(const float4*)(var + n);

    float4 out;
    float* op = &out.x;
    const float* bip = &bi.x; const float* gap = &ga.x; const float* bep = &be.x;
    const float* mup = &mu.x; const float* vap = &va.x;
#pragma unroll
    for (int j = 0; j < 4; ++j) {
        const float* w = W1 + (size_t)(n + j) * 8;
        float4 w0 = *(const float4*)(w + 0);
        float4 w1 = *(const float4*)(w + 4);
        float d = g0.x*w0.x + g0.y*w0.y + g0.z*w0.z + g0.w*w0.w
                + g1.x*w1.x + g1.y*w1.y + g1.z*w1.z + g1.w*w1.w;
        float s  = gap[j] * rsqrtf(vap[j] + BN_EPS_F);
        float t0 = fmaf(s, bip[j] - mup[j], bep[j]);
        op[j] = fmaxf(fmaf(s, d, t0), 0.f);
    }
    *(float4*)(h1 + (size_t)m * 1000 + n) = out;
}

// ---------------------------------------------------------------------------
// fp32 NT GEMM — round-6 geometry (64Mx128N tile, BK=32, 256 thr = 4 waves
// 2x2; wave 32Mx64N; lane 4Mx8N) + two fixes:
//  (1) double-buffered LDS, register prefetch in round-1's proven-clean loop
//      shape (GLOAD(t+1) before MAC, LWRITE after barrier). No min-waves in
//      __launch_bounds__ (the ",2" 128-VGPR cap caused the r2-r4 spills).
//  (2) conflict-free staging writes: wave's 64 writes span 64 consecutive
//      rows -> 2 lanes/bank (free) instead of 4-way.
// Fragment reads: As broadcast+full-bank-spread, Bs 2-way — conflict-free.
// MODE 0: BN+relu, MODE 1: BN+sigmoid, MODE 2: raw partial (split-K via z).
// Requires: ldc >= (max col<N rounded to 8)+8; K,kchunk % 4 == 0.
// ---------------------------------------------------------------------------
template<int MODE>
__global__ __launch_bounds__(256)
void gemm_db(const float* __restrict__ A, int K, int lda,
             const float* __restrict__ B, int N, int ldb, int kchunk,
             const float* __restrict__ bias, const float* __restrict__ gamma,
             const float* __restrict__ beta, const float* __restrict__ mean,
             const float* __restrict__ var,
             float* __restrict__ C, int ldc, size_t zstride)
{
    __shared__ float As[2][32][68];
    __shared__ float Bs[2][32][132];

    const int tid  = threadIdx.x;
    const int w    = tid >> 6;
    const int lane = tid & 63;
    const int wx   = w & 1, wy = w >> 1;
    const int tx   = lane & 7, ty = lane >> 3;
    const int m0   = blockIdx.y * 64;
    const int n0   = blockIdx.x * 128;
    const int z    = blockIdx.z;
    const int ks   = z * kchunk;
    const int ke   = min(K, ks + kchunk);
    const int nt   = (ke - ks + 31) >> 5;

    // staging map: A row = tid&63, chunks {tid>>6, +4}; B row = tid&127,
    // chunks {tid>>7, +2, +4, +6}. Wave writes span 64 consecutive rows.
    const int a_r = tid & 63;
    const int a_c = tid >> 6;          // 0..3
    const int b_r = tid & 127;
    const int b_c = tid >> 7;          // 0..1
    const float* Arow = A + (size_t)(m0 + a_r) * lda;
    const float* Brow = B + (size_t)(n0 + b_r) * ldb;
    const bool bvalid = (n0 + b_r) < N;

    float4 pa0, pa1, pb0, pb1, pb2, pb3;
    const float4 zf4 = make_float4(0.f, 0.f, 0.f, 0.f);

    float acc[4][8];
#pragma unroll
    for (int i = 0; i < 4; ++i)
#pragma unroll
        for (int j = 0; j < 8; ++j) acc[i][j] = 0.f;

#define GLOAD(KT) do {                                                        \
    const int kt_ = (KT);                                                     \
    int kg_;                                                                  \
    kg_ = kt_ + (a_c    )*4; pa0 = (kg_<ke) ? *(const float4*)(Arow+kg_) : zf4;\
    kg_ = kt_ + (a_c + 4)*4; pa1 = (kg_<ke) ? *(const float4*)(Arow+kg_) : zf4;\
    kg_ = kt_ + (b_c    )*4; pb0 = (kg_<ke && bvalid) ? *(const float4*)(Brow+kg_) : zf4;\
    kg_ = kt_ + (b_c + 2)*4; pb1 = (kg_<ke && bvalid) ? *(const float4*)(Brow+kg_) : zf4;\
    kg_ = kt_ + (b_c + 4)*4; pb2 = (kg_<ke && bvalid) ? *(const float4*)(Brow+kg_) : zf4;\
    kg_ = kt_ + (b_c + 6)*4; pb3 = (kg_<ke && bvalid) ? *(const float4*)(Brow+kg_) : zf4;\
} while (0)

#define LWRITE(BUF) do {                                                      \
    As[BUF][4*a_c+0 ][a_r] = pa0.x; As[BUF][4*a_c+1 ][a_r] = pa0.y;           \
    As[BUF][4*a_c+2 ][a_r] = pa0.z; As[BUF][4*a_c+3 ][a_r] = pa0.w;           \
    As[BUF][4*a_c+16][a_r] = pa1.x; As[BUF][4*a_c+17][a_r] = pa1.y;           \
    As[BUF][4*a_c+18][a_r] = pa1.z; As[BUF][4*a_c+19][a_r] = pa1.w;           \
    Bs[BUF][4*b_c+0 ][b_r] = pb0.x; Bs[BUF][4*b_c+1 ][b_r] = pb0.y;           \
    Bs[BUF][4*b_c+2 ][b_r] = pb0.z; Bs[BUF][4*b_c+3 ][b_r] = pb0.w;           \
    Bs[BUF][4*b_c+8 ][b_r] = pb1.x; Bs[BUF][4*b_c+9 ][b_r] = pb1.y;           \
    Bs[BUF][4*b_c+10][b_r] = pb1.z; Bs[BUF][4*b_c+11][b_r] = pb1.w;           \
    Bs[BUF][4*b_c+16][b_r] = pb2.x; Bs[BUF][4*b_c+17][b_r] = pb2.y;           \
    Bs[BUF][4*b_c+18][b_r] = pb2.z; Bs[BUF][4*b_c+19][b_r] = pb2.w;           \
    Bs[BUF][4*b_c+24][b_r] = pb3.x; Bs[BUF][4*b_c+25][b_r] = pb3.y;           \
    Bs[BUF][4*b_c+26][b_r] = pb3.z; Bs[BUF][4*b_c+27][b_r] = pb3.w;           \
} while (0)

    GLOAD(ks);
    LWRITE(0);
    __syncthreads();

    const int ar = wy * 32 + ty * 4;
    const int br = wx * 64 + tx * 8;

    for (int t = 0; t < nt; ++t) {
        const int cur = t & 1;
        if (t + 1 < nt) GLOAD(ks + (t + 1) * 32);
#pragma unroll 4
        for (int kk = 0; kk < 32; ++kk) {
            float4 av = *(const float4*)&As[cur][kk][ar];
            float4 y0 = *(const float4*)&Bs[cur][kk][br];
            float4 y1 = *(const float4*)&Bs[cur][kk][br + 4];
            float a[4] = {av.x, av.y, av.z, av.w};
            float b[8] = {y0.x,y0.y,y0.z,y0.w,y1.x,y1.y,y1.z,y1.w};
#pragma unroll
            for (int i = 0; i < 4; ++i)
#pragma unroll
                for (int j = 0; j < 8; ++j)
                    acc[i][j] = fmaf(a[i], b[j], acc[i][j]);
        }
        __syncthreads();
        if (t + 1 < nt) {
            LWRITE(cur ^ 1);
            __syncthreads();
        }
    }
#undef GLOAD
#undef LWRITE

    // ---- epilogue ----
    const int row0 = m0 + ar;
    const int col  = n0 + br;
    if (col < N) {     // col%8==0; ldc guarantees col..col+7 in-bounds;
                       // cols >= N hold zeros (B staged 0) and are never read
        if (MODE == 2) {
            float* Cz = C + (size_t)z * zstride;
#pragma unroll
            for (int i = 0; i < 4; ++i) {
                float* cr = Cz + (size_t)(row0 + i) * ldc + col;
                *(float4*)(cr)     = make_float4(acc[i][0],acc[i][1],acc[i][2],acc[i][3]);
                *(float4*)(cr + 4) = make_float4(acc[i][4],acc[i][5],acc[i][6],acc[i][7]);
            }
        } else {
            float4 ga0 = *(const float4*)(gamma + col);
            float4 va0 = *(const float4*)(var + col);
            float4 bi0 = *(const float4*)(bias + col);
            float4 mu0 = *(const float4*)(mean + col);
            float4 be0 = *(const float4*)(beta + col);
            float4 ga1 = *(const float4*)(gamma + col + 4);
            float4 va1 = *(const float4*)(var + col + 4);
            float4 bi1 = *(const float4*)(bias + col + 4);
            float4 mu1 = *(const float4*)(mean + col + 4);
            float4 be1 = *(const float4*)(beta + col + 4);
            float s[8], t8[8];
            s[0]=ga0.x*rsqrtf(va0.x+BN_EPS_F); s[1]=ga0.y*rsqrtf(va0.y+BN_EPS_F);
            s[2]=ga0.z*rsqrtf(va0.z+BN_EPS_F); s[3]=ga0.w*rsqrtf(va0.w+BN_EPS_F);
            s[4]=ga1.x*rsqrtf(va1.x+BN_EPS_F); s[5]=ga1.y*rsqrtf(va1.y+BN_EPS_F);
            s[6]=ga1.z*rsqrtf(va1.z+BN_EPS_F); s[7]=ga1.w*rsqrtf(va1.w+BN_EPS_F);
            t8[0]=fmaf(s[0],bi0.x-mu0.x,be0.x); t8[1]=fmaf(s[1],bi0.y-mu0.y,be0.y);
            t8[2]=fmaf(s[2],bi0.z-mu0.z,be0.z); t8[3]=fmaf(s[3],bi0.w-mu0.w,be0.w);
            t8[4]=fmaf(s[4],bi1.x-mu1.x,be1.x); t8[5]=fmaf(s[5],bi1.y-mu1.y,be1.y);
            t8[6]=fmaf(s[6],bi1.z-mu1.z,be1.z); t8[7]=fmaf(s[7],bi1.w-mu1.w,be1.w);
#pragma unroll
            for (int i = 0; i < 4; ++i) {
                float y[8];
#pragma unroll
                for (int j = 0; j < 8; ++j) {
                    float yy = fmaf(s[j], acc[i][j], t8[j]);
                    if (MODE == 0) yy = fmaxf(yy, 0.f);
                    else           yy = 1.f / (1.f + expf(-yy));
                    y[j] = yy;
                }
                float* cr = C + (size_t)(row0 + i) * ldc + col;
                *(float4*)(cr)     = make_float4(y[0],y[1],y[2],y[3]);
                *(float4*)(cr + 4) = make_float4(y[4],y[5],y[6],y[7]);
            }
        }
    }
}

// ---------------------------------------------------------------------------
// Split-K=2 reduce for layer 2 + BN + relu. Writes h2 over PANEL 1 (in-place
// same-index), freeing [0 .. panel1) contiguously for GEMM3 partials.
// ---------------------------------------------------------------------------
__global__ __launch_bounds__(256)
void reduce2_relu(float* __restrict__ part,     // panel0; panel1 at +2048000
                  const float* __restrict__ bias, const float* __restrict__ gamma,
                  const float* __restrict__ beta, const float* __restrict__ mean,
                  const float* __restrict__ var)
{
    const int i = blockIdx.x * 256 + threadIdx.x;
    if (i >= 2048 * 250) return;
    const int m = i / 250;
    const int n = (i % 250) * 4;
    const size_t off = (size_t)m * 1000 + n;
    float4 a = *(const float4*)(part + off);
    float4 b = *(const float4*)(part + 2048000 + off);
    float4 ga = *(const float4*)(gamma + n);
    float4 va = *(const float4*)(var + n);
    float4 bi = *(const float4*)(bias + n);
    float4 mu = *(const float4*)(mean + n);
    float4 be = *(const float4*)(beta + n);
    float s0 = ga.x*rsqrtf(va.x+BN_EPS_F), s1 = ga.y*rsqrtf(va.y+BN_EPS_F);
    float s2 = ga.z*rsqrtf(va.z+BN_EPS_F), s3 = ga.w*rsqrtf(va.w+BN_EPS_F);
    float4 out;
    out.x = fmaxf(fmaf(s0, a.x + b.x + bi.x - mu.x, be.x), 0.f);
    out.y = fmaxf(fmaf(s1, a.y + b.y + bi.y - mu.y, be.y), 0.f);
    out.z = fmaxf(fmaf(s2, a.z + b.z + bi.z - mu.z, be.z), 0.f);
    out.w = fmaxf(fmaf(s3, a.w + b.w + bi.w - mu.w, be.w), 0.f);
    *(float4*)(part + 2048000 + off) = out;     // h2 = panel1
}

// ---------------------------------------------------------------------------
// Split-K reduce for layer 3 + BN + sigmoid -> p (2048 x 300)
// ---------------------------------------------------------------------------
__global__ __launch_bounds__(256)
void reduce3_sigmoid(const float* __restrict__ part, int nz, size_t pstride,
                     const float* __restrict__ bias, const float* __restrict__ gamma,
                     const float* __restrict__ beta, const float* __restrict__ mean,
                     const float* __restrict__ var, float* __restrict__ p)
{
    const int i = blockIdx.x * 256 + threadIdx.x;
    if (i >= 2048 * 75) return;
    const int m = i / 75;
    const int n = (i % 75) * 4;
    const size_t off = (size_t)m * 304 + n;
    float d0 = 0.f, d1 = 0.f, d2 = 0.f, d3 = 0.f;
    for (int zz = 0; zz < nz; ++zz) {
        float4 v = *(const float4*)(part + zz * pstride + off);
        d0 += v.x; d1 += v.y; d2 += v.z; d3 += v.w;
    }
    float4 ga = *(const float4*)(gamma + n);
    float4 va = *(const float4*)(var + n);
    float4 bi = *(const float4*)(bias + n);
    float4 mu = *(const float4*)(mean + n);
    float4 be = *(const float4*)(beta + n);
    float s0 = ga.x*rsqrtf(va.x+BN_EPS_F), s1 = ga.y*rsqrtf(va.y+BN_EPS_F);
    float s2 = ga.z*rsqrtf(va.z+BN_EPS_F), s3 = ga.w*rsqrtf(va.w+BN_EPS_F);
    float4 out;
    out.x = 1.f/(1.f+expf(-(fmaf(s0, d0 + bi.x - mu.x, be.x))));
    out.y = 1.f/(1.f+expf(-(fmaf(s1, d1 + bi.y - mu.y, be.y))));
    out.z = 1.f/(1.f+expf(-(fmaf(s2, d2 + bi.z - mu.z, be.z))));
    out.w = 1.f/(1.f+expf(-(fmaf(s3, d3 + bi.w - mu.w, be.w))));
    *(float4*)(p + (size_t)m * 300 + n) = out;
}

// ---------------------------------------------------------------------------
// Lorentz spectrum: one block per batch row; oscillator params packed as
// float4 in LDS (1 ds_read_b128 per oscillator).
// ---------------------------------------------------------------------------
__global__ __launch_bounds__(320)
void lorentz_kernel(const float* __restrict__ P,     // 2048 x 300
                    const float* __restrict__ G,     // 2048 x 8
                    const float* __restrict__ wgrid, // 300
                    float* __restrict__ T)           // 2048 x 300
{
    __shared__ float4 s_pk[100];   // {w0^2, wp^2, wp^2*g, g^2}
    const int b   = blockIdx.x;
    const int tid = threadIdx.x;
    if (tid < 100) {
        const float* p = P + (size_t)b*300 + 3*tid;
        const float w0 = p[0]*5.f;
        const float wp = p[1]*5.f;
        const float g  = p[2]*0.5f;
        s_pk[tid] = make_float4(w0*w0, wp*wp, wp*wp*g, g*g);
    }
    __syncthreads();
    if (tid < 300) {
        const float wg = wgrid[tid];
        const float w2 = wg*wg;
        float e1 = 0.f, e2s = 0.f;
#pragma unroll 10
        for (int l = 0; l < 100; ++l) {
            const float4 v    = s_pk[l];
            const float s1    = v.x - w2;
            const float denom = fmaf(s1, s1, w2 * v.w);
            const float r     = __builtin_amdgcn_rcpf(denom);
            e1  = fmaf(v.y*s1, r, e1);
            e2s = fmaf(v.z,    r, e2s);
        }
        e1 += 10.f;
        const float e2  = e2s * wg;
        const float mag = sqrtf(fmaf(e1, e1, e2*e2));
        const float nn  = sqrtf(0.5f*(mag + e1));
        const float kk  = sqrtf(fmaxf(0.5f*(mag - e1), 0.f));
        const float d   = fmaxf(fmaxf(G[b*8+4], G[b*8+5]),
                                fmaxf(G[b*8+6], G[b*8+7]));
        const float ab  = expf(-0.006283185307179586f * d * kk);
        const float np1 = nn + 1.f;
        const float Tv  = 4.f*nn / fmaf(np1, np1, kk*kk) * ab;
        T[(size_t)b*300 + tid] = Tv;
    }
}

extern "C" void kernel_launch(void* const* d_in, const int* in_sizes, int n_in,
                              void* d_out, int out_size, void* d_ws, size_t ws_size,
                              hipStream_t stream) {
    const float* G      = (const float*)d_in[0];
    const float* W1     = (const float*)d_in[1];
    const float* b1     = (const float*)d_in[2];
    const float* gamma1 = (const float*)d_in[3];
    const float* beta1  = (const float*)d_in[4];
    const float* mean1  = (const float*)d_in[5];
    const float* var1   = (const float*)d_in[6];
    const float* W2     = (const float*)d_in[7];
    const float* b2     = (const float*)d_in[8];
    const float* gamma2 = (const float*)d_in[9];
    const float* beta2  = (const float*)d_in[10];
    const float* mean2  = (const float*)d_in[11];
    const float* var2   = (const float*)d_in[12];
    const float* W3     = (const float*)d_in[13];
    const float* b3     = (const float*)d_in[14];
    const float* gamma3 = (const float*)d_in[15];
    const float* beta3  = (const float*)d_in[16];
    const float* mean3  = (const float*)d_in[17];
    const float* var3   = (const float*)d_in[18];
    const float* wgrid  = (const float*)d_in[19];

    float* ws = (float*)d_ws;
    float* T  = (float*)d_out;

    // Layout (24.576 MB total — proven in rounds 5-7):
    //   h1    @ [0          .. 2,048,000)
    //   part2 @ [2,048,000  .. 6,144,000)  2 panels; h2 = panel1 (in-place)
    //   part3 @ [0          .. 3,112,960)  5 panels (over dead h1+panel0)
    //   p     @ [3,112,960  .. 3,727,360)  (over dead panel0 tail)
    float* h1    = ws;
    float* part2 = ws + 2048000;
    float* h2    = ws + 4096000;       // = part2 panel1
    float* part3 = ws;
    float* p     = ws + 3112960;

    // Layer 1 (K=8, memory-bound)
    l1_kernel<<<2048, 256, 0, stream>>>(G, W1, b1, gamma1, beta1, mean1, var1, h1);

    // Layer 2: split-K=2 (grid 8n x 32m x 2z = 512 blocks x 4 waves = 8 w/CU)
    gemm_db<2><<<dim3(8, 32, 2), 256, 0, stream>>>(
        h1, 1000, 1000, W2, 1000, 1000, 500,
        nullptr, nullptr, nullptr, nullptr, nullptr, part2, 1000, 2048000);
    reduce2_relu<<<2000, 256, 0, stream>>>(part2, b2, gamma2, beta2, mean2, var2);

    // Layer 3: split-K=5 (grid 3n x 32m x 5z = 480 blocks x 4 waves)
    gemm_db<2><<<dim3(3, 32, 5), 256, 0, stream>>>(
        h2, 1000, 1000, W3, 300, 1000, 200,
        nullptr, nullptr, nullptr, nullptr, nullptr, part3, 304, 622592);

    // Reduce partials + BN + sigmoid -> p
    reduce3_sigmoid<<<600, 256, 0, stream>>>(part3, 5, 622592,
        b3, gamma3, beta3, mean3, var3, p);

    // Lorentz spectrum -> T
    lorentz_kernel<<<2048, 320, 0, stream>>>(p, G, wgrid, T);
}

// Round 9
// 151.853 us; speedup vs baseline: 1.5782x; 1.2870x over previous
//
#include <hip/hip_runtime.h>
#include <math.h>

#define BN_EPS_F 1e-5f

// ---------------------------------------------------------------------------
// Layer 1: K=8 — memory-bound, one thread per 4 outputs.
// ---------------------------------------------------------------------------
__global__ __launch_bounds__(256)
void l1_kernel(const float* __restrict__ G, const float* __restrict__ W1,
               const float* __restrict__ bias, const float* __restrict__ gamma,
               const float* __restrict__ beta, const float* __restrict__ mean,
               const float* __restrict__ var, float* __restrict__ h1)
{
    const int m = blockIdx.x;
    const int t = threadIdx.x;
    if (t >= 250) return;
    const int n = 4 * t;

    float4 g0 = *(const float4*)(G + (size_t)m * 8 + 0);
    float4 g1 = *(const float4*)(G + (size_t)m * 8 + 4);

    float4 bi = *(const float4*)(bias + n);
    float4 ga = *(const float4*)(gamma + n);
    float4 be = *(const float4*)(beta + n);
    float4 mu = *(const float4*)(mean + n);
    float4 va = *(const float4*)(var + n);

    float4 out;
    float* op = &out.x;
    const float* bip = &bi.x; const float* gap = &ga.x; const float* bep = &be.x;
    const float* mup = &mu.x; const float* vap = &va.x;
#pragma unroll
    for (int j = 0; j < 4; ++j) {
        const float* w = W1 + (size_t)(n + j) * 8;
        float4 w0 = *(const float4*)(w + 0);
        float4 w1 = *(const float4*)(w + 4);
        float d = g0.x*w0.x + g0.y*w0.y + g0.z*w0.z + g0.w*w0.w
                + g1.x*w1.x + g1.y*w1.y + g1.z*w1.z + g1.w*w1.w;
        float s  = gap[j] * rsqrtf(vap[j] + BN_EPS_F);
        float t0 = fmaf(s, bip[j] - mup[j], bep[j]);
        op[j] = fmaxf(fmaf(s, d, t0), 0.f);
    }
    *(float4*)(h1 + (size_t)m * 1000 + n) = out;
}

// ---------------------------------------------------------------------------
// fp32 NT GEMM — r6 geometry (64Mx128N tile, BK=32, 256 thr = 4 waves 2x2;
// wave 32Mx64N; lane 4Mx8N) + r6 COALESCED staging map (lanes 0-7 read 8
// consecutive float4 of one row -> 128B segments) + r8 double-buffer loop
// (GLOAD(t+1) before MAC, LWRITE after barrier; proven spill-free, VGPR 68).
// The 4-way LDS write conflict of the transposed store is accepted (~8%).
// MODE 0: BN+relu, MODE 1: BN+sigmoid, MODE 2: raw partial (split-K via z).
// Requires: ldc >= last float4 end; K,kchunk % 4 == 0.
// ---------------------------------------------------------------------------
template<int MODE>
__global__ __launch_bounds__(256)
void gemm_db(const float* __restrict__ A, int K, int lda,
             const float* __restrict__ B, int N, int ldb, int kchunk,
             const float* __restrict__ bias, const float* __restrict__ gamma,
             const float* __restrict__ beta, const float* __restrict__ mean,
             const float* __restrict__ var,
             float* __restrict__ C, int ldc, size_t zstride)
{
    __shared__ float As[2][32][68];
    __shared__ float Bs[2][32][132];

    const int tid  = threadIdx.x;
    const int w    = tid >> 6;
    const int lane = tid & 63;
    const int wx   = w & 1, wy = w >> 1;
    const int tx   = lane & 7, ty = lane >> 3;
    const int m0   = blockIdx.y * 64;
    const int n0   = blockIdx.x * 128;
    const int z    = blockIdx.z;
    const int ks   = z * kchunk;
    const int ke   = min(K, ks + kchunk);
    const int nt   = (ke - ks + 31) >> 5;

    const int srow = tid >> 3;     // 0..31
    const int skq  = tid & 7;      // 16B chunk within BK=32

    const float* Ar0 = A + (size_t)(m0 + srow)      * lda;
    const float* Ar1 = A + (size_t)(m0 + srow + 32) * lda;
    const float* Br0 = B + (size_t)(n0 + srow)      * ldb;
    const float* Br1 = B + (size_t)(n0 + srow + 32) * ldb;
    const float* Br2 = B + (size_t)(n0 + srow + 64) * ldb;
    const float* Br3 = B + (size_t)(n0 + srow + 96) * ldb;
    const bool bb0 = (n0 + srow)      < N;
    const bool bb1 = (n0 + srow + 32) < N;
    const bool bb2 = (n0 + srow + 64) < N;
    const bool bb3 = (n0 + srow + 96) < N;

    float4 pa0, pa1, pb0, pb1, pb2, pb3;
    const float4 zf4 = make_float4(0.f, 0.f, 0.f, 0.f);

    float acc[4][8];
#pragma unroll
    for (int i = 0; i < 4; ++i)
#pragma unroll
        for (int j = 0; j < 8; ++j) acc[i][j] = 0.f;

#define GLOAD(KT) do {                                                        \
    const int kg_ = (KT) + 4 * skq;                                           \
    const bool kv_ = kg_ < ke;                                                \
    pa0 = kv_          ? *(const float4*)(Ar0 + kg_) : zf4;                   \
    pa1 = kv_          ? *(const float4*)(Ar1 + kg_) : zf4;                   \
    pb0 = (kv_ && bb0) ? *(const float4*)(Br0 + kg_) : zf4;                   \
    pb1 = (kv_ && bb1) ? *(const float4*)(Br1 + kg_) : zf4;                   \
    pb2 = (kv_ && bb2) ? *(const float4*)(Br2 + kg_) : zf4;                   \
    pb3 = (kv_ && bb3) ? *(const float4*)(Br3 + kg_) : zf4;                   \
} while (0)

#define LWRITE(BUF) do {                                                      \
    As[BUF][4*skq+0][srow]    = pa0.x; As[BUF][4*skq+1][srow]    = pa0.y;     \
    As[BUF][4*skq+2][srow]    = pa0.z; As[BUF][4*skq+3][srow]    = pa0.w;     \
    As[BUF][4*skq+0][srow+32] = pa1.x; As[BUF][4*skq+1][srow+32] = pa1.y;     \
    As[BUF][4*skq+2][srow+32] = pa1.z; As[BUF][4*skq+3][srow+32] = pa1.w;     \
    Bs[BUF][4*skq+0][srow]    = pb0.x; Bs[BUF][4*skq+1][srow]    = pb0.y;     \
    Bs[BUF][4*skq+2][srow]    = pb0.z; Bs[BUF][4*skq+3][srow]    = pb0.w;     \
    Bs[BUF][4*skq+0][srow+32] = pb1.x; Bs[BUF][4*skq+1][srow+32] = pb1.y;     \
    Bs[BUF][4*skq+2][srow+32] = pb1.z; Bs[BUF][4*skq+3][srow+32] = pb1.w;     \
    Bs[BUF][4*skq+0][srow+64] = pb2.x; Bs[BUF][4*skq+1][srow+64] = pb2.y;     \
    Bs[BUF][4*skq+2][srow+64] = pb2.z; Bs[BUF][4*skq+3][srow+64] = pb2.w;     \
    Bs[BUF][4*skq+0][srow+96] = pb3.x; Bs[BUF][4*skq+1][srow+96] = pb3.y;     \
    Bs[BUF][4*skq+2][srow+96] = pb3.z; Bs[BUF][4*skq+3][srow+96] = pb3.w;     \
} while (0)

    GLOAD(ks);
    LWRITE(0);
    __syncthreads();

    const int ar = wy * 32 + ty * 4;
    const int br = wx * 64 + tx * 8;

    for (int t = 0; t < nt; ++t) {
        const int cur = t & 1;
        if (t + 1 < nt) GLOAD(ks + (t + 1) * 32);
#pragma unroll 4
        for (int kk = 0; kk < 32; ++kk) {
            float4 av = *(const float4*)&As[cur][kk][ar];
            float4 y0 = *(const float4*)&Bs[cur][kk][br];
            float4 y1 = *(const float4*)&Bs[cur][kk][br + 4];
            float a[4] = {av.x, av.y, av.z, av.w};
            float b[8] = {y0.x,y0.y,y0.z,y0.w,y1.x,y1.y,y1.z,y1.w};
#pragma unroll
            for (int i = 0; i < 4; ++i)
#pragma unroll
                for (int j = 0; j < 8; ++j)
                    acc[i][j] = fmaf(a[i], b[j], acc[i][j]);
        }
        __syncthreads();
        if (t + 1 < nt) {
            LWRITE(cur ^ 1);
            __syncthreads();
        }
    }
#undef GLOAD
#undef LWRITE

    // ---- epilogue ----
    const int row0 = m0 + ar;
    const int col  = n0 + br;
    if (col < N) {     // col%8==0; ldc guarantees col..col+7 in-bounds;
                       // cols >= N hold zeros (B staged 0) and are never read
        if (MODE == 2) {
            float* Cz = C + (size_t)z * zstride;
#pragma unroll
            for (int i = 0; i < 4; ++i) {
                float* cr = Cz + (size_t)(row0 + i) * ldc + col;
                *(float4*)(cr)     = make_float4(acc[i][0],acc[i][1],acc[i][2],acc[i][3]);
                *(float4*)(cr + 4) = make_float4(acc[i][4],acc[i][5],acc[i][6],acc[i][7]);
            }
        } else {
            float4 ga0 = *(const float4*)(gamma + col);
            float4 va0 = *(const float4*)(var + col);
            float4 bi0 = *(const float4*)(bias + col);
            float4 mu0 = *(const float4*)(mean + col);
            float4 be0 = *(const float4*)(beta + col);
            float4 ga1 = *(const float4*)(gamma + col + 4);
            float4 va1 = *(const float4*)(var + col + 4);
            float4 bi1 = *(const float4*)(bias + col + 4);
            float4 mu1 = *(const float4*)(mean + col + 4);
            float4 be1 = *(const float4*)(beta + col + 4);
            float s[8], t8[8];
            s[0]=ga0.x*rsqrtf(va0.x+BN_EPS_F); s[1]=ga0.y*rsqrtf(va0.y+BN_EPS_F);
            s[2]=ga0.z*rsqrtf(va0.z+BN_EPS_F); s[3]=ga0.w*rsqrtf(va0.w+BN_EPS_F);
            s[4]=ga1.x*rsqrtf(va1.x+BN_EPS_F); s[5]=ga1.y*rsqrtf(va1.y+BN_EPS_F);
            s[6]=ga1.z*rsqrtf(va1.z+BN_EPS_F); s[7]=ga1.w*rsqrtf(va1.w+BN_EPS_F);
            t8[0]=fmaf(s[0],bi0.x-mu0.x,be0.x); t8[1]=fmaf(s[1],bi0.y-mu0.y,be0.y);
            t8[2]=fmaf(s[2],bi0.z-mu0.z,be0.z); t8[3]=fmaf(s[3],bi0.w-mu0.w,be0.w);
            t8[4]=fmaf(s[4],bi1.x-mu1.x,be1.x); t8[5]=fmaf(s[5],bi1.y-mu1.y,be1.y);
            t8[6]=fmaf(s[6],bi1.z-mu1.z,be1.z); t8[7]=fmaf(s[7],bi1.w-mu1.w,be1.w);
#pragma unroll
            for (int i = 0; i < 4; ++i) {
                float y[8];
#pragma unroll
                for (int j = 0; j < 8; ++j) {
                    float yy = fmaf(s[j], acc[i][j], t8[j]);
                    if (MODE == 0) yy = fmaxf(yy, 0.f);
                    else           yy = 1.f / (1.f + expf(-yy));
                    y[j] = yy;
                }
                float* cr = C + (size_t)(row0 + i) * ldc + col;
                *(float4*)(cr)     = make_float4(y[0],y[1],y[2],y[3]);
                *(float4*)(cr + 4) = make_float4(y[4],y[5],y[6],y[7]);
            }
        }
    }
}

// ---------------------------------------------------------------------------
// Split-K=2 reduce for layer 2 + BN + relu. Writes h2 over PANEL 1 (in-place
// same-index), freeing [0 .. panel1) contiguously for GEMM3 partials.
// ---------------------------------------------------------------------------
__global__ __launch_bounds__(256)
void reduce2_relu(float* __restrict__ part,     // panel0; panel1 at +2048000
                  const float* __restrict__ bias, const float* __restrict__ gamma,
                  const float* __restrict__ beta, const float* __restrict__ mean,
                  const float* __restrict__ var)
{
    const int i = blockIdx.x * 256 + threadIdx.x;
    if (i >= 2048 * 250) return;
    const int m = i / 250;
    const int n = (i % 250) * 4;
    const size_t off = (size_t)m * 1000 + n;
    float4 a = *(const float4*)(part + off);
    float4 b = *(const float4*)(part + 2048000 + off);
    float4 ga = *(const float4*)(gamma + n);
    float4 va = *(const float4*)(var + n);
    float4 bi = *(const float4*)(bias + n);
    float4 mu = *(const float4*)(mean + n);
    float4 be = *(const float4*)(beta + n);
    float s0 = ga.x*rsqrtf(va.x+BN_EPS_F), s1 = ga.y*rsqrtf(va.y+BN_EPS_F);
    float s2 = ga.z*rsqrtf(va.z+BN_EPS_F), s3 = ga.w*rsqrtf(va.w+BN_EPS_F);
    float4 out;
    out.x = fmaxf(fmaf(s0, a.x + b.x + bi.x - mu.x, be.x), 0.f);
    out.y = fmaxf(fmaf(s1, a.y + b.y + bi.y - mu.y, be.y), 0.f);
    out.z = fmaxf(fmaf(s2, a.z + b.z + bi.z - mu.z, be.z), 0.f);
    out.w = fmaxf(fmaf(s3, a.w + b.w + bi.w - mu.w, be.w), 0.f);
    *(float4*)(part + 2048000 + off) = out;     // h2 = panel1
}

// ---------------------------------------------------------------------------
// FUSED: split-K5 reduce for layer 3 + BN + sigmoid + Lorentz spectrum.
// One block per batch row. Threads 0-299 first reduce their own column of
// the 5 partial panels and produce p[n] into LDS; then 100 threads pack
// oscillator params; then 300 threads run the spectral loop.
// ---------------------------------------------------------------------------
__global__ __launch_bounds__(320)
void lorentz_fused(const float* __restrict__ part,   // 5 panels, stride pstride, ld 304
                   size_t pstride,
                   const float* __restrict__ bias, const float* __restrict__ gamma,
                   const float* __restrict__ beta, const float* __restrict__ mean,
                   const float* __restrict__ var,
                   const float* __restrict__ G,     // 2048 x 8
                   const float* __restrict__ wgrid, // 300
                   float* __restrict__ T)           // 2048 x 300
{
    __shared__ float  s_p[304];
    __shared__ float4 s_pk[100];   // {w0^2, wp^2, wp^2*g, g^2}
    const int b   = blockIdx.x;
    const int tid = threadIdx.x;

    if (tid < 300) {
        const size_t off = (size_t)b * 304 + tid;
        float d = part[off];
        d += part[pstride     + off];
        d += part[2*pstride   + off];
        d += part[3*pstride   + off];
        d += part[4*pstride   + off];
        const float s  = gamma[tid] * rsqrtf(var[tid] + BN_EPS_F);
        const float y  = fmaf(s, d + bias[tid] - mean[tid], beta[tid]);
        s_p[tid] = 1.f / (1.f + expf(-y));
    }
    __syncthreads();
    if (tid < 100) {
        const float w0 = s_p[3*tid    ] * 5.f;
        const float wp = s_p[3*tid + 1] * 5.f;
        const float g  = s_p[3*tid + 2] * 0.5f;
        s_pk[tid] = make_float4(w0*w0, wp*wp, wp*wp*g, g*g);
    }
    __syncthreads();
    if (tid < 300) {
        const float wg = wgrid[tid];
        const float w2 = wg*wg;
        float e1 = 0.f, e2s = 0.f;
#pragma unroll 10
        for (int l = 0; l < 100; ++l) {
            const float4 v    = s_pk[l];
            const float s1    = v.x - w2;
            const float denom = fmaf(s1, s1, w2 * v.w);
            const float r     = __builtin_amdgcn_rcpf(denom);
            e1  = fmaf(v.y*s1, r, e1);
            e2s = fmaf(v.z,    r, e2s);
        }
        e1 += 10.f;
        const float e2  = e2s * wg;
        const float mag = sqrtf(fmaf(e1, e1, e2*e2));
        const float nn  = sqrtf(0.5f*(mag + e1));
        const float kk  = sqrtf(fmaxf(0.5f*(mag - e1), 0.f));
        const float d   = fmaxf(fmaxf(G[b*8+4], G[b*8+5]),
                                fmaxf(G[b*8+6], G[b*8+7]));
        const float ab  = expf(-0.006283185307179586f * d * kk);
        const float np1 = nn + 1.f;
        const float Tv  = 4.f*nn / fmaf(np1, np1, kk*kk) * ab;
        T[(size_t)b*300 + tid] = Tv;
    }
}

extern "C" void kernel_launch(void* const* d_in, const int* in_sizes, int n_in,
                              void* d_out, int out_size, void* d_ws, size_t ws_size,
                              hipStream_t stream) {
    const float* G      = (const float*)d_in[0];
    const float* W1     = (const float*)d_in[1];
    const float* b1     = (const float*)d_in[2];
    const float* gamma1 = (const float*)d_in[3];
    const float* beta1  = (const float*)d_in[4];
    const float* mean1  = (const float*)d_in[5];
    const float* var1   = (const float*)d_in[6];
    const float* W2     = (const float*)d_in[7];
    const float* b2     = (const float*)d_in[8];
    const float* gamma2 = (const float*)d_in[9];
    const float* beta2  = (const float*)d_in[10];
    const float* mean2  = (const float*)d_in[11];
    const float* var2   = (const float*)d_in[12];
    const float* W3     = (const float*)d_in[13];
    const float* b3     = (const float*)d_in[14];
    const float* gamma3 = (const float*)d_in[15];
    const float* beta3  = (const float*)d_in[16];
    const float* mean3  = (const float*)d_in[17];
    const float* var3   = (const float*)d_in[18];
    const float* wgrid  = (const float*)d_in[19];

    float* ws = (float*)d_ws;
    float* T  = (float*)d_out;

    // Layout (24.576 MB total — proven in rounds 5-8):
    //   h1    @ [0          .. 2,048,000)
    //   part2 @ [2,048,000  .. 6,144,000)  2 panels; h2 = panel1 (in-place)
    //   part3 @ [0          .. 3,112,960)  5 panels (over dead h1 + panel0)
    float* h1    = ws;
    float* part2 = ws + 2048000;
    float* h2    = ws + 4096000;       // = part2 panel1
    float* part3 = ws;

    // Layer 1 (K=8, memory-bound)
    l1_kernel<<<2048, 256, 0, stream>>>(G, W1, b1, gamma1, beta1, mean1, var1, h1);

    // Layer 2: split-K=2 (grid 8n x 32m x 2z = 512 blocks x 4 waves = 8 w/CU)
    gemm_db<2><<<dim3(8, 32, 2), 256, 0, stream>>>(
        h1, 1000, 1000, W2, 1000, 1000, 500,
        nullptr, nullptr, nullptr, nullptr, nullptr, part2, 1000, 2048000);
    reduce2_relu<<<2000, 256, 0, stream>>>(part2, b2, gamma2, beta2, mean2, var2);

    // Layer 3: split-K=5 (grid 3n x 32m x 5z = 480 blocks x 4 waves)
    gemm_db<2><<<dim3(3, 32, 5), 256, 0, stream>>>(
        h2, 1000, 1000, W3, 300, 1000, 200,
        nullptr, nullptr, nullptr, nullptr, nullptr, part3, 304, 622592);

    // Fused reduce3 + BN + sigmoid + Lorentz spectrum -> T
    lorentz_fused<<<2048, 320, 0, stream>>>(part3, 622592,
        b3, gamma3, beta3, mean3, var3, G, wgrid, T);
}

// Round 10
// 144.191 us; speedup vs baseline: 1.6621x; 1.0531x over previous
//
#include <hip/hip_runtime.h>
#include <math.h>

#define BN_EPS_F 1e-5f

// ---------------------------------------------------------------------------
// Layer 1: K=8 — memory-bound, one thread per 4 outputs.
// ---------------------------------------------------------------------------
__global__ __launch_bounds__(256)
void l1_kernel(const float* __restrict__ G, const float* __restrict__ W1,
               const float* __restrict__ bias, const float* __restrict__ gamma,
               const float* __restrict__ beta, const float* __restrict__ mean,
               const float* __restrict__ var, float* __restrict__ h1)
{
    const int m = blockIdx.x;
    const int t = threadIdx.x;
    if (t >= 250) return;
    const int n = 4 * t;

    float4 g0 = *(const float4*)(G + (size_t)m * 8 + 0);
    float4 g1 = *(const float4*)(G + (size_t)m * 8 + 4);

    float4 bi = *(const float4*)(bias + n);
    float4 ga = *(const float4*)(gamma + n);
    float4 be = *(const float4*)(beta + n);
    float4 mu = *(const float4*)(mean + n);
    float4 va = *(const float4*)(var + n);

    float4 out;
    float* op = &out.x;
    const float* bip = &bi.x; const float* gap = &ga.x; const float* bep = &be.x;
    const float* mup = &mu.x; const float* vap = &va.x;
#pragma unroll
    for (int j = 0; j < 4; ++j) {
        const float* w = W1 + (size_t)(n + j) * 8;
        float4 w0 = *(const float4*)(w + 0);
        float4 w1 = *(const float4*)(w + 4);
        float d = g0.x*w0.x + g0.y*w0.y + g0.z*w0.z + g0.w*w0.w
                + g1.x*w1.x + g1.y*w1.y + g1.z*w1.z + g1.w*w1.w;
        float s  = gap[j] * rsqrtf(vap[j] + BN_EPS_F);
        float t0 = fmaf(s, bip[j] - mup[j], bep[j]);
        op[j] = fmaxf(fmaf(s, d, t0), 0.f);
    }
    *(float4*)(h1 + (size_t)m * 1000 + n) = out;
}

// ---------------------------------------------------------------------------
// fp32 NT GEMM — 128(M) x 128(N) tile, BK=32, 256 thr = 4 waves (2x2); wave
// owns 64Mx64N; lane (8x8 grid) computes 8Mx8N (rows ty*4+{0..3} and +32).
// Per kk: 4 x ds_read_b128 per 64 FMA = 1.0 B/FMA (LDS-pipe optimal).
// r9 double-buffer loop (GLOAD(t+1) before MAC, LWRITE after barrier) with
// r6 coalesced staging (lanes 0-7 read 8 consecutive float4 of one row).
// Pad = 2 (ld 130): staging writes 2-way (free), A-reads conflict-free,
// B-reads 2-way (free). LDS 66.5 KB -> 2 blocks/CU. No VGPR cap.
// Raw partial store only (split-K via z). Requires N%8==0 coverage via
// ldc >= last written float4 end; K,kchunk % 4 == 0; M % 128 == 0.
// ---------------------------------------------------------------------------
__global__ __launch_bounds__(256)
void gemm128(const float* __restrict__ A, int K, int lda,
             const float* __restrict__ B, int N, int ldb, int kchunk,
             float* __restrict__ C, int ldc, size_t zstride)
{
    __shared__ float As[2][32][130];
    __shared__ float Bs[2][32][130];

    const int tid  = threadIdx.x;
    const int w    = tid >> 6;
    const int lane = tid & 63;
    const int wx   = w & 1, wy = w >> 1;
    const int tx   = lane & 7, ty = lane >> 3;
    const int m0   = blockIdx.y * 128;
    const int n0   = blockIdx.x * 128;
    const int z    = blockIdx.z;
    const int ks   = z * kchunk;
    const int ke   = min(K, ks + kchunk);
    const int nt   = (ke - ks + 31) >> 5;

    const int srow = tid >> 3;     // 0..31
    const int skq  = tid & 7;      // 16B chunk within BK=32

    const float* Ar0 = A + (size_t)(m0 + srow)      * lda;
    const float* Ar1 = A + (size_t)(m0 + srow + 32) * lda;
    const float* Ar2 = A + (size_t)(m0 + srow + 64) * lda;
    const float* Ar3 = A + (size_t)(m0 + srow + 96) * lda;
    const float* Br0 = B + (size_t)(n0 + srow)      * ldb;
    const float* Br1 = B + (size_t)(n0 + srow + 32) * ldb;
    const float* Br2 = B + (size_t)(n0 + srow + 64) * ldb;
    const float* Br3 = B + (size_t)(n0 + srow + 96) * ldb;
    const bool bb0 = (n0 + srow)      < N;
    const bool bb1 = (n0 + srow + 32) < N;
    const bool bb2 = (n0 + srow + 64) < N;
    const bool bb3 = (n0 + srow + 96) < N;

    float4 pa0, pa1, pa2, pa3, pb0, pb1, pb2, pb3;
    const float4 zf4 = make_float4(0.f, 0.f, 0.f, 0.f);

    float acc[8][8];
#pragma unroll
    for (int i = 0; i < 8; ++i)
#pragma unroll
        for (int j = 0; j < 8; ++j) acc[i][j] = 0.f;

#define GLOAD(KT) do {                                                        \
    const int kg_ = (KT) + 4 * skq;                                           \
    const bool kv_ = kg_ < ke;                                                \
    pa0 = kv_          ? *(const float4*)(Ar0 + kg_) : zf4;                   \
    pa1 = kv_          ? *(const float4*)(Ar1 + kg_) : zf4;                   \
    pa2 = kv_          ? *(const float4*)(Ar2 + kg_) : zf4;                   \
    pa3 = kv_          ? *(const float4*)(Ar3 + kg_) : zf4;                   \
    pb0 = (kv_ && bb0) ? *(const float4*)(Br0 + kg_) : zf4;                   \
    pb1 = (kv_ && bb1) ? *(const float4*)(Br1 + kg_) : zf4;                   \
    pb2 = (kv_ && bb2) ? *(const float4*)(Br2 + kg_) : zf4;                   \
    pb3 = (kv_ && bb3) ? *(const float4*)(Br3 + kg_) : zf4;                   \
} while (0)

#define LWRITE(BUF) do {                                                      \
    As[BUF][4*skq+0][srow]    = pa0.x; As[BUF][4*skq+1][srow]    = pa0.y;     \
    As[BUF][4*skq+2][srow]    = pa0.z; As[BUF][4*skq+3][srow]    = pa0.w;     \
    As[BUF][4*skq+0][srow+32] = pa1.x; As[BUF][4*skq+1][srow+32] = pa1.y;     \
    As[BUF][4*skq+2][srow+32] = pa1.z; As[BUF][4*skq+3][srow+32] = pa1.w;     \
    As[BUF][4*skq+0][srow+64] = pa2.x; As[BUF][4*skq+1][srow+64] = pa2.y;     \
    As[BUF][4*skq+2][srow+64] = pa2.z; As[BUF][4*skq+3][srow+64] = pa2.w;     \
    As[BUF][4*skq+0][srow+96] = pa3.x; As[BUF][4*skq+1][srow+96] = pa3.y;     \
    As[BUF][4*skq+2][srow+96] = pa3.z; As[BUF][4*skq+3][srow+96] = pa3.w;     \
    Bs[BUF][4*skq+0][srow]    = pb0.x; Bs[BUF][4*skq+1][srow]    = pb0.y;     \
    Bs[BUF][4*skq+2][srow]    = pb0.z; Bs[BUF][4*skq+3][srow]    = pb0.w;     \
    Bs[BUF][4*skq+0][srow+32] = pb1.x; Bs[BUF][4*skq+1][srow+32] = pb1.y;     \
    Bs[BUF][4*skq+2][srow+32] = pb1.z; Bs[BUF][4*skq+3][srow+32] = pb1.w;     \
    Bs[BUF][4*skq+0][srow+64] = pb2.x; Bs[BUF][4*skq+1][srow+64] = pb2.y;     \
    Bs[BUF][4*skq+2][srow+64] = pb2.z; Bs[BUF][4*skq+3][srow+64] = pb2.w;     \
    Bs[BUF][4*skq+0][srow+96] = pb3.x; Bs[BUF][4*skq+1][srow+96] = pb3.y;     \
    Bs[BUF][4*skq+2][srow+96] = pb3.z; Bs[BUF][4*skq+3][srow+96] = pb3.w;     \
} while (0)

    GLOAD(ks);
    LWRITE(0);
    __syncthreads();

    const int ar = wy * 64 + ty * 4;   // rows ar..ar+3 and ar+32..ar+35
    const int br = wx * 64 + tx * 8;   // cols br..br+7

    for (int t = 0; t < nt; ++t) {
        const int cur = t & 1;
        if (t + 1 < nt) GLOAD(ks + (t + 1) * 32);
#pragma unroll 4
        for (int kk = 0; kk < 32; ++kk) {
            float4 x0 = *(const float4*)&As[cur][kk][ar];
            float4 x1 = *(const float4*)&As[cur][kk][ar + 32];
            float4 y0 = *(const float4*)&Bs[cur][kk][br];
            float4 y1 = *(const float4*)&Bs[cur][kk][br + 4];
            float a[8] = {x0.x,x0.y,x0.z,x0.w,x1.x,x1.y,x1.z,x1.w};
            float b[8] = {y0.x,y0.y,y0.z,y0.w,y1.x,y1.y,y1.z,y1.w};
#pragma unroll
            for (int i = 0; i < 8; ++i)
#pragma unroll
                for (int j = 0; j < 8; ++j)
                    acc[i][j] = fmaf(a[i], b[j], acc[i][j]);
        }
        __syncthreads();
        if (t + 1 < nt) {
            LWRITE(cur ^ 1);
            __syncthreads();
        }
    }
#undef GLOAD
#undef LWRITE

    // ---- epilogue: raw partial store ----
    const int col = n0 + br;
    if (col < N) {     // col%8==0, N%8==0 -> whole 8-col group valid;
                       // ldc padding guarantees the float4s are in-bounds
        float* Cz = C + (size_t)z * zstride;
#pragma unroll
        for (int i = 0; i < 8; ++i) {
            const int row = m0 + ar + (i < 4 ? i : 28 + i);   // +0..3, +32..35
            float* cr = Cz + (size_t)row * ldc + col;
            *(float4*)(cr)     = make_float4(acc[i][0],acc[i][1],acc[i][2],acc[i][3]);
            *(float4*)(cr + 4) = make_float4(acc[i][4],acc[i][5],acc[i][6],acc[i][7]);
        }
    }
}

// ---------------------------------------------------------------------------
// Split-K reduce for layer 2 + BN + relu. Reads nz panels, writes h2 over the
// LAST panel (in-place same-index: read all panels first, then write).
// ---------------------------------------------------------------------------
__global__ __launch_bounds__(256)
void reduce2_relu(float* __restrict__ part, int nz,
                  const float* __restrict__ bias, const float* __restrict__ gamma,
                  const float* __restrict__ beta, const float* __restrict__ mean,
                  const float* __restrict__ var)
{
    const int i = blockIdx.x * 256 + threadIdx.x;
    if (i >= 2048 * 250) return;
    const int m = i / 250;
    const int n = (i % 250) * 4;
    const size_t off = (size_t)m * 1000 + n;
    float d0 = 0.f, d1 = 0.f, d2 = 0.f, d3 = 0.f;
    for (int zz = 0; zz < nz; ++zz) {
        float4 v = *(const float4*)(part + (size_t)zz * 2048000 + off);
        d0 += v.x; d1 += v.y; d2 += v.z; d3 += v.w;
    }
    float4 ga = *(const float4*)(gamma + n);
    float4 va = *(const float4*)(var + n);
    float4 bi = *(const float4*)(bias + n);
    float4 mu = *(const float4*)(mean + n);
    float4 be = *(const float4*)(beta + n);
    float s0 = ga.x*rsqrtf(va.x+BN_EPS_F), s1 = ga.y*rsqrtf(va.y+BN_EPS_F);
    float s2 = ga.z*rsqrtf(va.z+BN_EPS_F), s3 = ga.w*rsqrtf(va.w+BN_EPS_F);
    float4 out;
    out.x = fmaxf(fmaf(s0, d0 + bi.x - mu.x, be.x), 0.f);
    out.y = fmaxf(fmaf(s1, d1 + bi.y - mu.y, be.y), 0.f);
    out.z = fmaxf(fmaf(s2, d2 + bi.z - mu.z, be.z), 0.f);
    out.w = fmaxf(fmaf(s3, d3 + bi.w - mu.w, be.w), 0.f);
    *(float4*)(part + (size_t)(nz - 1) * 2048000 + off) = out;   // h2 = last panel
}

// ---------------------------------------------------------------------------
// FUSED: split-K5 reduce for layer 3 + BN + sigmoid + Lorentz spectrum.
// ---------------------------------------------------------------------------
__global__ __launch_bounds__(320)
void lorentz_fused(const float* __restrict__ part,   // 5 panels, stride pstride, ld 304
                   size_t pstride,
                   const float* __restrict__ bias, const float* __restrict__ gamma,
                   const float* __restrict__ beta, const float* __restrict__ mean,
                   const float* __restrict__ var,
                   const float* __restrict__ G,     // 2048 x 8
                   const float* __restrict__ wgrid, // 300
                   float* __restrict__ T)           // 2048 x 300
{
    __shared__ float  s_p[304];
    __shared__ float4 s_pk[100];   // {w0^2, wp^2, wp^2*g, g^2}
    const int b   = blockIdx.x;
    const int tid = threadIdx.x;

    if (tid < 300) {
        const size_t off = (size_t)b * 304 + tid;
        float d = part[off];
        d += part[pstride     + off];
        d += part[2*pstride   + off];
        d += part[3*pstride   + off];
        d += part[4*pstride   + off];
        const float s  = gamma[tid] * rsqrtf(var[tid] + BN_EPS_F);
        const float y  = fmaf(s, d + bias[tid] - mean[tid], beta[tid]);
        s_p[tid] = 1.f / (1.f + expf(-y));
    }
    __syncthreads();
    if (tid < 100) {
        const float w0 = s_p[3*tid    ] * 5.f;
        const float wp = s_p[3*tid + 1] * 5.f;
        const float g  = s_p[3*tid + 2] * 0.5f;
        s_pk[tid] = make_float4(w0*w0, wp*wp, wp*wp*g, g*g);
    }
    __syncthreads();
    if (tid < 300) {
        const float wg = wgrid[tid];
        const float w2 = wg*wg;
        float e1 = 0.f, e2s = 0.f;
#pragma unroll 10
        for (int l = 0; l < 100; ++l) {
            const float4 v    = s_pk[l];
            const float s1    = v.x - w2;
            const float denom = fmaf(s1, s1, w2 * v.w);
            const float r     = __builtin_amdgcn_rcpf(denom);
            e1  = fmaf(v.y*s1, r, e1);
            e2s = fmaf(v.z,    r, e2s);
        }
        e1 += 10.f;
        const float e2  = e2s * wg;
        const float mag = sqrtf(fmaf(e1, e1, e2*e2));
        const float nn  = sqrtf(0.5f*(mag + e1));
        const float kk  = sqrtf(fmaxf(0.5f*(mag - e1), 0.f));
        const float d   = fmaxf(fmaxf(G[b*8+4], G[b*8+5]),
                                fmaxf(G[b*8+6], G[b*8+7]));
        const float ab  = expf(-0.006283185307179586f * d * kk);
        const float np1 = nn + 1.f;
        const float Tv  = 4.f*nn / fmaf(np1, np1, kk*kk) * ab;
        T[(size_t)b*300 + tid] = Tv;
    }
}

extern "C" void kernel_launch(void* const* d_in, const int* in_sizes, int n_in,
                              void* d_out, int out_size, void* d_ws, size_t ws_size,
                              hipStream_t stream) {
    const float* G      = (const float*)d_in[0];
    const float* W1     = (const float*)d_in[1];
    const float* b1     = (const float*)d_in[2];
    const float* gamma1 = (const float*)d_in[3];
    const float* beta1  = (const float*)d_in[4];
    const float* mean1  = (const float*)d_in[5];
    const float* var1   = (const float*)d_in[6];
    const float* W2     = (const float*)d_in[7];
    const float* b2     = (const float*)d_in[8];
    const float* gamma2 = (const float*)d_in[9];
    const float* beta2  = (const float*)d_in[10];
    const float* mean2  = (const float*)d_in[11];
    const float* var2   = (const float*)d_in[12];
    const float* W3     = (const float*)d_in[13];
    const float* b3     = (const float*)d_in[14];
    const float* gamma3 = (const float*)d_in[15];
    const float* beta3  = (const float*)d_in[16];
    const float* mean3  = (const float*)d_in[17];
    const float* var3   = (const float*)d_in[18];
    const float* wgrid  = (const float*)d_in[19];

    float* ws = (float*)d_ws;
    float* T  = (float*)d_out;

    // Base layout (proven 24.576 MB):
    //   h1    @ [0          .. 2,048,000)
    //   part2 @ [2,048,000  .. 2,048,000 + nz2*2,048,000)
    //   h2    = last part2 panel (written in place by reduce2)
    //   part3 @ [0 .. 3,112,960)  5 panels over dead h1 (+panel0)
    float* h1    = ws;
    float* part2 = ws + 2048000;
    float* part3 = ws;

    // Deterministic path choice on session-constant ws_size.
    const bool big = ws_size >= (size_t)40960000;   // split-K4 needs 10.24M floats
    const int  nz2 = big ? 4 : 2;
    float* h2 = part2 + (size_t)(nz2 - 1) * 2048000;

    // Layer 1 (K=8, memory-bound)
    l1_kernel<<<2048, 256, 0, stream>>>(G, W1, b1, gamma1, beta1, mean1, var1, h1);

    // Layer 2: 2048x1000 K=1000 -> partials (grid 8n x 16m x nz2)
    if (big) {
        gemm128<<<dim3(8, 16, 4), 256, 0, stream>>>(
            h1, 1000, 1000, W2, 1000, 1000, 252, part2, 1000, 2048000);
    } else {
        gemm128<<<dim3(8, 16, 2), 256, 0, stream>>>(
            h1, 1000, 1000, W2, 1000, 1000, 500, part2, 1000, 2048000);
    }
    reduce2_relu<<<2000, 256, 0, stream>>>(part2, nz2, b2, gamma2, beta2, mean2, var2);

    // Layer 3: 2048x300 K=1000, split-K=5 (grid 3n x 16m x 5z = 240 blocks)
    gemm128<<<dim3(3, 16, 5), 256, 0, stream>>>(
        h2, 1000, 1000, W3, 300, 1000, 200, part3, 304, 622592);

    // Fused reduce3 + BN + sigmoid + Lorentz spectrum -> T
    lorentz_fused<<<2048, 320, 0, stream>>>(part3, 622592,
        b3, gamma3, beta3, mean3, var3, G, wgrid, T);
}

// Round 11
// 89.025 us; speedup vs baseline: 2.6920x; 1.6197x over previous
//
#include <hip/hip_runtime.h>
#include <hip/hip_bf16.h>
#include <math.h>

#define BN_EPS_F 1e-5f

typedef __attribute__((ext_vector_type(8))) short short8v;   // 8 bf16 = 4 VGPR
typedef __attribute__((ext_vector_type(4))) float floatx4;   // MFMA C/D

// split fp32 -> bf16 hi + bf16 lo  (x ~= hi + lo, rel err ~2^-17)
__device__ __forceinline__ void split2(float x, short& h, short& l) {
    __hip_bfloat16 bh = __float2bfloat16(x);
    float hf = __bfloat162float(bh);
    __hip_bfloat16 bl = __float2bfloat16(x - hf);
    h = __builtin_bit_cast(short, bh);
    l = __builtin_bit_cast(short, bl);
}

// ---------------------------------------------------------------------------
// Layer 1: K=8, memory-bound. Emits h1 directly as bf16 hi/lo, ld 1024,
// cols 1000..1023 zeroed (K-pad for the MFMA GEMM).
// ---------------------------------------------------------------------------
__global__ __launch_bounds__(256)
void l1_kernel(const float* __restrict__ G, const float* __restrict__ W1,
               const float* __restrict__ bias, const float* __restrict__ gamma,
               const float* __restrict__ beta, const float* __restrict__ mean,
               const float* __restrict__ var,
               short* __restrict__ h1h, short* __restrict__ h1l)
{
    const int m = blockIdx.x;
    const int t = threadIdx.x;
    const int n = 4 * t;
    short4 hh = {0,0,0,0}, ll = {0,0,0,0};
    if (t < 250) {
        float4 g0 = *(const float4*)(G + (size_t)m * 8 + 0);
        float4 g1 = *(const float4*)(G + (size_t)m * 8 + 4);
        float4 bi = *(const float4*)(bias + n);
        float4 ga = *(const float4*)(gamma + n);
        float4 be = *(const float4*)(beta + n);
        float4 mu = *(const float4*)(mean + n);
        float4 va = *(const float4*)(var + n);
        float y[4];
        const float* bip = &bi.x; const float* gap = &ga.x; const float* bep = &be.x;
        const float* mup = &mu.x; const float* vap = &va.x;
#pragma unroll
        for (int j = 0; j < 4; ++j) {
            const float* wp = W1 + (size_t)(n + j) * 8;
            float4 w0 = *(const float4*)(wp + 0);
            float4 w1 = *(const float4*)(wp + 4);
            float d = g0.x*w0.x + g0.y*w0.y + g0.z*w0.z + g0.w*w0.w
                    + g1.x*w1.x + g1.y*w1.y + g1.z*w1.z + g1.w*w1.w;
            float s  = gap[j] * rsqrtf(vap[j] + BN_EPS_F);
            float t0 = fmaf(s, bip[j] - mup[j], bep[j]);
            y[j] = fmaxf(fmaf(s, d, t0), 0.f);
        }
        split2(y[0], hh.x, ll.x); split2(y[1], hh.y, ll.y);
        split2(y[2], hh.z, ll.z); split2(y[3], hh.w, ll.w);
    }
    *(short4*)&h1h[(size_t)m * 1024 + n] = hh;
    *(short4*)&h1l[(size_t)m * 1024 + n] = ll;
}

// ---------------------------------------------------------------------------
// Weight conversion: fp32 [.. x 1000, ld 1000] -> bf16 hi/lo [R x 1024],
// zero-padded rows >= nrows and cols >= 1000. One block per output row.
// ---------------------------------------------------------------------------
__global__ __launch_bounds__(256)
void conv_split(const float* __restrict__ src, int nrows,
                short* __restrict__ dh, short* __restrict__ dl)
{
    const int row = blockIdx.x;
    const int c = 4 * threadIdx.x;
    short4 hh = {0,0,0,0}, ll = {0,0,0,0};
    if (row < nrows && c < 1000) {
        float4 v = *(const float4*)(src + (size_t)row * 1000 + c);
        split2(v.x, hh.x, ll.x); split2(v.y, hh.y, ll.y);
        split2(v.z, hh.z, ll.z); split2(v.w, hh.w, ll.w);
    }
    *(short4*)&dh[(size_t)row * 1024 + c] = hh;
    *(short4*)&dl[(size_t)row * 1024 + c] = ll;
}

// ---------------------------------------------------------------------------
// Split-bf16 MFMA NT GEMM: C_partial = Ah*Bh^T + Ah*Bl^T + Al*Bh^T.
// A,B bf16 [rows x 1024] (K-padded). Tile 128Mx128N, BK=32, 256 thr = 4
// waves (2x2); wave owns 64x64 = 4x4 mfma_f32_16x16x32_bf16 tiles.
// Fragment layouts (m89-verified): A/B lane l -> row/col l&15, k=(l>>4)*8+j;
// D lane l -> col l&15, row (l>>4)*4+r.
// LDS [row][40] shorts: frag reads uniform across banks; 16B-aligned.
// r9 double-buffer loop shape (no cross-barrier reg liveness except the
// prefetch regs, proven spill-free pattern). Raw partial store (split-K z).
// ---------------------------------------------------------------------------
__global__ __launch_bounds__(256)
void gemm_mfma(const short* __restrict__ Ah, const short* __restrict__ Al,
               const short* __restrict__ Bh, const short* __restrict__ Bl,
               int kchunk, float* __restrict__ C, int ldc, size_t zstride)
{
    __shared__ short LAh[2][128][40], LAl[2][128][40];
    __shared__ short LBh[2][128][40], LBl[2][128][40];

    const int tid  = threadIdx.x;
    const int w    = tid >> 6, lane = tid & 63;
    const int wx   = w & 1,  wy = w >> 1;
    const int fr   = lane & 15, fq = lane >> 4;
    const int m0   = blockIdx.y * 128;
    const int n0   = blockIdx.x * 128;
    const int z    = blockIdx.z;
    const int ks   = z * kchunk;
    const int nt   = kchunk >> 5;

    const int srow = tid >> 1;          // 0..127
    const int soff = (tid & 1) * 16;    // 16-short (32B) half of a 64B row-chunk

    const short* gAh = Ah + (size_t)(m0 + srow) * 1024 + soff;
    const short* gAl = Al + (size_t)(m0 + srow) * 1024 + soff;
    const short* gBh = Bh + (size_t)(n0 + srow) * 1024 + soff;
    const short* gBl = Bl + (size_t)(n0 + srow) * 1024 + soff;

    int4 sah0, sah1, sal0, sal1, sbh0, sbh1, sbl0, sbl1;

    floatx4 acc[4][4];
#pragma unroll
    for (int i = 0; i < 4; ++i)
#pragma unroll
        for (int j = 0; j < 4; ++j) acc[i][j] = (floatx4){0.f,0.f,0.f,0.f};

#define GLOAD(KT) do {                                                        \
    const int kt_ = (KT);                                                     \
    sah0 = *(const int4*)(gAh + kt_);  sah1 = *(const int4*)(gAh + kt_ + 8);  \
    sal0 = *(const int4*)(gAl + kt_);  sal1 = *(const int4*)(gAl + kt_ + 8);  \
    sbh0 = *(const int4*)(gBh + kt_);  sbh1 = *(const int4*)(gBh + kt_ + 8);  \
    sbl0 = *(const int4*)(gBl + kt_);  sbl1 = *(const int4*)(gBl + kt_ + 8);  \
} while (0)

#define LWRITE(BUF) do {                                                      \
    *(int4*)&LAh[BUF][srow][soff]     = sah0;                                 \
    *(int4*)&LAh[BUF][srow][soff + 8] = sah1;                                 \
    *(int4*)&LAl[BUF][srow][soff]     = sal0;                                 \
    *(int4*)&LAl[BUF][srow][soff + 8] = sal1;                                 \
    *(int4*)&LBh[BUF][srow][soff]     = sbh0;                                 \
    *(int4*)&LBh[BUF][srow][soff + 8] = sbh1;                                 \
    *(int4*)&LBl[BUF][srow][soff]     = sbl0;                                 \
    *(int4*)&LBl[BUF][srow][soff + 8] = sbl1;                                 \
} while (0)

    GLOAD(ks);
    LWRITE(0);
    __syncthreads();

    const int arow = wy * 64 + fr;
    const int brow = wx * 64 + fr;
    const int kq   = fq * 8;

    for (int t = 0; t < nt; ++t) {
        const int cur = t & 1;
        if (t + 1 < nt) GLOAD(ks + (t + 1) * 32);

        short8v ah[4], al[4], bh[4], bl[4];
#pragma unroll
        for (int mi = 0; mi < 4; ++mi) {
            ah[mi] = *(const short8v*)&LAh[cur][arow + mi*16][kq];
            al[mi] = *(const short8v*)&LAl[cur][arow + mi*16][kq];
        }
#pragma unroll
        for (int nj = 0; nj < 4; ++nj) {
            bh[nj] = *(const short8v*)&LBh[cur][brow + nj*16][kq];
            bl[nj] = *(const short8v*)&LBl[cur][brow + nj*16][kq];
        }
#pragma unroll
        for (int mi = 0; mi < 4; ++mi)
#pragma unroll
            for (int nj = 0; nj < 4; ++nj) {
                acc[mi][nj] = __builtin_amdgcn_mfma_f32_16x16x32_bf16(
                                  ah[mi], bh[nj], acc[mi][nj], 0, 0, 0);
                acc[mi][nj] = __builtin_amdgcn_mfma_f32_16x16x32_bf16(
                                  ah[mi], bl[nj], acc[mi][nj], 0, 0, 0);
                acc[mi][nj] = __builtin_amdgcn_mfma_f32_16x16x32_bf16(
                                  al[mi], bh[nj], acc[mi][nj], 0, 0, 0);
            }
        __syncthreads();
        if (t + 1 < nt) {
            LWRITE(cur ^ 1);
            __syncthreads();
        }
    }
#undef GLOAD
#undef LWRITE

    // ---- epilogue: raw partial store (D: col=lane&15, row=(lane>>4)*4+r)
    float* Cz = C + (size_t)z * zstride;
    const int fq4 = fq * 4;
#pragma unroll
    for (int mi = 0; mi < 4; ++mi) {
        const int rbase = m0 + wy * 64 + mi * 16 + fq4;
#pragma unroll
        for (int nj = 0; nj < 4; ++nj) {
            const int col = n0 + wx * 64 + nj * 16 + fr;
#pragma unroll
            for (int r = 0; r < 4; ++r)
                Cz[(size_t)(rbase + r) * ldc + col] = acc[mi][nj][r];
        }
    }
}

// ---------------------------------------------------------------------------
// Split-K=2 reduce for layer 2 + BN + relu -> h2 as bf16 hi/lo (ld 1024,
// cols >= 1000 zeroed).
// ---------------------------------------------------------------------------
__global__ __launch_bounds__(256)
void reduce2_split(const float* __restrict__ part,   // 2 panels, ld 1024
                   const float* __restrict__ bias, const float* __restrict__ gamma,
                   const float* __restrict__ beta, const float* __restrict__ mean,
                   const float* __restrict__ var,
                   short* __restrict__ h2h, short* __restrict__ h2l)
{
    const int i = blockIdx.x * 256 + threadIdx.x;    // grid = 2048 blocks
    const int m = i >> 8;
    const int n = (i & 255) * 4;
    short4 hh = {0,0,0,0}, ll = {0,0,0,0};
    if (n < 1000) {
        const size_t off = (size_t)m * 1024 + n;
        float4 a = *(const float4*)(part + off);
        float4 b = *(const float4*)(part + 2097152 + off);
        float4 ga = *(const float4*)(gamma + n);
        float4 va = *(const float4*)(var + n);
        float4 bi = *(const float4*)(bias + n);
        float4 mu = *(const float4*)(mean + n);
        float4 be = *(const float4*)(beta + n);
        float s0 = ga.x*rsqrtf(va.x+BN_EPS_F), s1 = ga.y*rsqrtf(va.y+BN_EPS_F);
        float s2 = ga.z*rsqrtf(va.z+BN_EPS_F), s3 = ga.w*rsqrtf(va.w+BN_EPS_F);
        float y0 = fmaxf(fmaf(s0, a.x + b.x + bi.x - mu.x, be.x), 0.f);
        float y1 = fmaxf(fmaf(s1, a.y + b.y + bi.y - mu.y, be.y), 0.f);
        float y2 = fmaxf(fmaf(s2, a.z + b.z + bi.z - mu.z, be.z), 0.f);
        float y3 = fmaxf(fmaf(s3, a.w + b.w + bi.w - mu.w, be.w), 0.f);
        split2(y0, hh.x, ll.x); split2(y1, hh.y, ll.y);
        split2(y2, hh.z, ll.z); split2(y3, hh.w, ll.w);
    }
    *(short4*)&h2h[(size_t)m * 1024 + n] = hh;
    *(short4*)&h2l[(size_t)m * 1024 + n] = ll;
}

// ---------------------------------------------------------------------------
// FUSED: split-K4 reduce for layer 3 + BN + sigmoid + Lorentz spectrum.
// part3: 4 panels, ld 384.
// ---------------------------------------------------------------------------
__global__ __launch_bounds__(320)
void lorentz_fused(const float* __restrict__ part, size_t pstride,
                   const float* __restrict__ bias, const float* __restrict__ gamma,
                   const float* __restrict__ beta, const float* __restrict__ mean,
                   const float* __restrict__ var,
                   const float* __restrict__ G,     // 2048 x 8
                   const float* __restrict__ wgrid, // 300
                   float* __restrict__ T)           // 2048 x 300
{
    __shared__ float  s_p[304];
    __shared__ float4 s_pk[100];   // {w0^2, wp^2, wp^2*g, g^2}
    const int b   = blockIdx.x;
    const int tid = threadIdx.x;

    if (tid < 300) {
        const size_t off = (size_t)b * 384 + tid;
        float d = part[off];
        d += part[pstride     + off];
        d += part[2*pstride   + off];
        d += part[3*pstride   + off];
        const float s = gamma[tid] * rsqrtf(var[tid] + BN_EPS_F);
        const float y = fmaf(s, d + bias[tid] - mean[tid], beta[tid]);
        s_p[tid] = 1.f / (1.f + expf(-y));
    }
    __syncthreads();
    if (tid < 100) {
        const float w0 = s_p[3*tid    ] * 5.f;
        const float wp = s_p[3*tid + 1] * 5.f;
        const float g  = s_p[3*tid + 2] * 0.5f;
        s_pk[tid] = make_float4(w0*w0, wp*wp, wp*wp*g, g*g);
    }
    __syncthreads();
    if (tid < 300) {
        const float wg = wgrid[tid];
        const float w2 = wg*wg;
        float e1 = 0.f, e2s = 0.f;
#pragma unroll 10
        for (int l = 0; l < 100; ++l) {
            const float4 v    = s_pk[l];
            const float s1    = v.x - w2;
            const float denom = fmaf(s1, s1, w2 * v.w);
            const float r     = __builtin_amdgcn_rcpf(denom);
            e1  = fmaf(v.y*s1, r, e1);
            e2s = fmaf(v.z,    r, e2s);
        }
        e1 += 10.f;
        const float e2  = e2s * wg;
        const float mag = sqrtf(fmaf(e1, e1, e2*e2));
        const float nn  = sqrtf(0.5f*(mag + e1));
        const float kk  = sqrtf(fmaxf(0.5f*(mag - e1), 0.f));
        const float d   = fmaxf(fmaxf(G[b*8+4], G[b*8+5]),
                                fmaxf(G[b*8+6], G[b*8+7]));
        const float ab  = expf(-0.006283185307179586f * d * kk);
        const float np1 = nn + 1.f;
        const float Tv  = 4.f*nn / fmaf(np1, np1, kk*kk) * ab;
        T[(size_t)b*300 + tid] = Tv;
    }
}

extern "C" void kernel_launch(void* const* d_in, const int* in_sizes, int n_in,
                              void* d_out, int out_size, void* d_ws, size_t ws_size,
                              hipStream_t stream) {
    const float* G      = (const float*)d_in[0];
    const float* W1     = (const float*)d_in[1];
    const float* b1     = (const float*)d_in[2];
    const float* gamma1 = (const float*)d_in[3];
    const float* beta1  = (const float*)d_in[4];
    const float* mean1  = (const float*)d_in[5];
    const float* var1   = (const float*)d_in[6];
    const float* W2     = (const float*)d_in[7];
    const float* b2     = (const float*)d_in[8];
    const float* gamma2 = (const float*)d_in[9];
    const float* beta2  = (const float*)d_in[10];
    const float* mean2  = (const float*)d_in[11];
    const float* var2   = (const float*)d_in[12];
    const float* W3     = (const float*)d_in[13];
    const float* b3     = (const float*)d_in[14];
    const float* gamma3 = (const float*)d_in[15];
    const float* beta3  = (const float*)d_in[16];
    const float* mean3  = (const float*)d_in[17];
    const float* var3   = (const float*)d_in[18];
    const float* wgrid  = (const float*)d_in[19];

    char*  wsb = (char*)d_ws;
    float* T   = (float*)d_out;

    // Layout, 39.32 MB total (ws >= 40.96 MB proven by round-10 big path):
    //   h1h   @ [0         ..  4,194,304)   2048x1024 bf16
    //   h1l   @ [4,194,304 ..  8,388,608)
    //   W2h   @ [8,388,608 .. 10,485,760)   1024x1024 bf16
    //   W2l   @ [10,485,760.. 12,582,912)
    //   part3 @ [0 .. 12,582,912)           4 x 2048x384 f32 (over dead h1/W2)
    //   part2 @ [12,582,912.. 29,360,128)   2 x 2048x1024 f32
    //   h2h   @ [29,360,128.. 33,554,432)   2048x1024 bf16
    //   h2l   @ [33,554,432.. 37,748,736)
    //   W3h   @ [37,748,736.. 38,535,168)   384x1024 bf16
    //   W3l   @ [38,535,168.. 39,321,600)
    short* h1h   = (short*)(wsb);
    short* h1l   = (short*)(wsb + 4194304);
    short* W2h   = (short*)(wsb + 8388608);
    short* W2l   = (short*)(wsb + 10485760);
    float* part3 = (float*)(wsb);
    float* part2 = (float*)(wsb + 12582912);
    short* h2h   = (short*)(wsb + 29360128);
    short* h2l   = (short*)(wsb + 33554432);
    short* W3h   = (short*)(wsb + 37748736);
    short* W3l   = (short*)(wsb + 38535168);

    // Layer 1 (K=8) -> h1 bf16 hi/lo
    l1_kernel<<<2048, 256, 0, stream>>>(G, W1, b1, gamma1, beta1, mean1, var1,
                                        h1h, h1l);
    // Weight conversions
    conv_split<<<1024, 256, 0, stream>>>(W2, 1000, W2h, W2l);
    conv_split<<<384, 256, 0, stream>>>(W3, 300, W3h, W3l);   // only rows 0..299 used

    // Layer 2: MFMA split-bf16, split-K=2 (grid 8n x 16m x 2z = 256 blocks)
    gemm_mfma<<<dim3(8, 16, 2), 256, 0, stream>>>(
        h1h, h1l, W2h, W2l, 512, part2, 1024, (size_t)2097152);

    // Reduce + BN + relu -> h2 bf16 hi/lo
    reduce2_split<<<2048, 256, 0, stream>>>(part2, b2, gamma2, beta2, mean2, var2,
                                            h2h, h2l);

    // Layer 3: MFMA split-bf16, split-K=4 (grid 3n x 16m x 4z = 192 blocks)
    gemm_mfma<<<dim3(3, 16, 4), 256, 0, stream>>>(
        h2h, h2l, W3h, W3l, 256, part3, 384, (size_t)786432);

    // Fused reduce3 + BN + sigmoid + Lorentz spectrum -> T
    lorentz_fused<<<2048, 320, 0, stream>>>(part3, (size_t)786432,
        b3, gamma3, beta3, mean3, var3, G, wgrid, T);
}